// Round 11
// baseline (240.779 us; speedup 1.0000x reference)
//
#include <hip/hip_runtime.h>
#include <cstdint>
#include <cstddef>

// Problem constants
#define NB 1024        // batch of triples
#define NE 50000       // entities
#define NE_PAD 50048   // padded to 391*128
#define DCOL 512       // dimension D
#define ATTN_C 8       // cores

static const size_t SCORES_OFF = (size_t)NB * NE;        // 51,200,000
static const size_t F1_OFF = SCORES_OFF + 0;
static const size_t F2_OFF = SCORES_OFF + 1;
static const size_t F3_OFF = SCORES_OFF + 2;
static const size_t ATTN_OFF = SCORES_OFF + 3;

typedef float f32x4 __attribute__((ext_vector_type(4)));
typedef short s16x8 __attribute__((ext_vector_type(8)));

__device__ __forceinline__ unsigned short f2bf(float f) {
  union { float f; uint32_t u; } x; x.f = f;
  uint32_t u = x.u;
  uint32_t r = (u + 0x7fffu + ((u >> 16) & 1u)) >> 16;  // RNE
  return (unsigned short)r;
}

__device__ __forceinline__ void gload16(const void* g, void* l) {
  __builtin_amdgcn_global_load_lds(
      (const __attribute__((address_space(1))) uint32_t*)g,
      (__attribute__((address_space(3))) uint32_t*)l, 16, 0, 0);
}

// counted vmcnt wait — N MUST equal loads-per-stage (2*FR), derived from the
// template (R6 lesson: a too-large hardcoded N is a no-op wait -> races).
template <int N>
__device__ __forceinline__ void waitcnt_vm() {
  static_assert(N == 0 || N == 4 || N == 8, "literal dispatch");
  if constexpr (N == 0) asm volatile("s_waitcnt vmcnt(0)" ::: "memory");
  else if constexpr (N == 4) asm volatile("s_waitcnt vmcnt(4)" ::: "memory");
  else if constexpr (N == 8) asm volatile("s_waitcnt vmcnt(8)" ::: "memory");
}

// ---------------------------------------------------------------------------
// K1 prep (small): blocks [0,1024) = gather h,r -> HR bf16 + n1;
// blocks [1024,1536) = transpose W1 -> bf16.  The entity_w->bf16 cvt moved
// into the triple_core launch (R10 lesson: as a serial pre-pass it blocks
// the MLP; fused with LDS/VALU-bound triple work it overlaps for free).
// ---------------------------------------------------------------------------
__global__ __launch_bounds__(256)
void prep(const int* __restrict__ heads, const int* __restrict__ rels,
          const int* __restrict__ tails, const float* __restrict__ ew,
          const float* __restrict__ rw, const float* __restrict__ w1,
          unsigned short* __restrict__ hrb, unsigned short* __restrict__ w1t,
          float* __restrict__ n1) {
  int tid = threadIdx.x;
  if (blockIdx.x < NB) {
    int b = blockIdx.x;
    const float* h = ew + (size_t)heads[b] * DCOL;
    const float* r = rw + (size_t)rels[b] * DCOL;
    const float* t = ew + (size_t)tails[b] * DCOL;
    float acc = 0.f;
    #pragma unroll
    for (int it = 0; it < 2; ++it) {
      int d = it * 256 + tid;
      float hv = h[d], rv = r[d], tv = t[d];
      hrb[(size_t)b * 1024 + d] = f2bf(hv);
      hrb[(size_t)b * 1024 + DCOL + d] = f2bf(rv);
      acc += hv * hv + rv * rv + tv * tv;
    }
    __shared__ float red[256];
    red[tid] = acc; __syncthreads();
    for (int s = 128; s > 0; s >>= 1) {
      if (tid < s) red[tid] += red[tid + s];
      __syncthreads();
    }
    if (tid == 0) n1[b] = red[0];
  } else {
    int tb = blockIdx.x - NB;          // 0..511
    int nb = (tb & 15) * 32, kb = (tb >> 4) * 32;
    __shared__ float tile[32][33];
    int tx = tid & 31, ty = tid >> 5;  // ty 0..7
    #pragma unroll
    for (int rr = 0; rr < 32; rr += 8)
      tile[ty + rr][tx] = w1[(size_t)(kb + ty + rr) * 512 + nb + tx];
    __syncthreads();
    #pragma unroll
    for (int rr = 0; rr < 32; rr += 8)
      w1t[(size_t)(nb + ty + rr) * 1024 + kb + tx] = f2bf(tile[tx][ty + rr]);
  }
}

// ---------------------------------------------------------------------------
// K2/K4: NT GEMM bf16 -> fp32 (exact R7 structure — best measured config).
// Tile (32*FR)^2, BK=64, 4 waves (2x2), mfma_f32_16x16x32_bf16, both operands
// via global_load_lds (width 16) with XOR-chunk source swizzle.
// Counted-vmcnt pipeline: raw s_barrier + s_waitcnt vmcnt(2*FR); the next
// tile's loads stay in flight ACROSS barriers. stage(kt+2) refills the freed
// buffer after the compute-barrier. sched_barrier(0) fences (rule #18).
// SWZ=1: XCD-ownership swizzle (bijective, MT*NT%8==0) -> each B-tile lives
// in exactly one per-XCD L2 (FETCH 403->71MB, R5).
// ---------------------------------------------------------------------------
template <int EPI, int FR, int SWZ, int MT>
__global__ __launch_bounds__(256, 2)
void gemm_nt(const unsigned short* __restrict__ A,
             const unsigned short* __restrict__ B,
             float* __restrict__ C, const float* __restrict__ bias,
             int K, int Nc, int NT) {
  constexpr int BM = FR * 32;            // tile size
  constexpr int TILE = BM * 128;         // bytes per operand tile (BK=64)
  __shared__ __align__(16) uint8_t smem[4 * TILE];  // [buf][A|B]
  const int tid = threadIdx.x;
  const int lane = tid & 63;
  const int wv = tid >> 6;
  const int wm = wv >> 1, wn = wv & 1;

  int m_t, n_t;
  if (SWZ) {
    int xcd = blockIdx.x & 7;
    int l = blockIdx.x >> 3;
    int w = xcd * ((MT * NT) >> 3) + l;  // bijective: MT*NT % 8 == 0
    n_t = w / MT; m_t = w % MT;
  } else {
    m_t = blockIdx.x % MT; n_t = blockIdx.x / MT;
  }
  const int m0 = m_t * BM;
  const int n0 = n_t * BM;
  const int rbytes = K * 2;

  f32x4 acc[FR][FR];
  #pragma unroll
  for (int i = 0; i < FR; ++i)
    #pragma unroll
    for (int j = 0; j < FR; ++j) acc[i][j] = (f32x4){0.f, 0.f, 0.f, 0.f};

  const int srow = lane >> 3;   // row within 8-row chunk
  const int scol = lane & 7;    // dest 16B unit within row
  const int nkt = K >> 6;       // K / 64

  auto stage = [&](int kt, int buf) {
    #pragma unroll
    for (int j = 0; j < FR; ++j) {
      const int chunk = wv * FR + j;
      const int r = chunk * 8 + srow;
      const int c = scol ^ (r & 7);
      gload16((const uint8_t*)A + (size_t)(m0 + r) * rbytes + kt * 128 + c * 16,
              &smem[buf * 2 * TILE + chunk * 1024]);
      gload16((const uint8_t*)B + (size_t)(n0 + r) * rbytes + kt * 128 + c * 16,
              &smem[buf * 2 * TILE + TILE + chunk * 1024]);
    }
  };
  auto compute = [&](int buf) {
    const uint8_t* sa = &smem[buf * 2 * TILE];
    const uint8_t* sb = sa + TILE;
    #pragma unroll
    for (int kk = 0; kk < 2; ++kk) {
      s16x8 af[FR], bfv[FR];
      #pragma unroll
      for (int f = 0; f < FR; ++f) {
        const int ra = wm * 16 * FR + f * 16 + (lane & 15);
        const int ca = (kk * 4 + (lane >> 4)) ^ (ra & 7);
        af[f] = *(const s16x8*)&sa[ra * 128 + ca * 16];
        const int rb = wn * 16 * FR + f * 16 + (lane & 15);
        const int cb = (kk * 4 + (lane >> 4)) ^ (rb & 7);
        bfv[f] = *(const s16x8*)&sb[rb * 128 + cb * 16];
      }
      #pragma unroll
      for (int fm = 0; fm < FR; ++fm)
        #pragma unroll
        for (int fn = 0; fn < FR; ++fn)
          acc[fm][fn] = __builtin_amdgcn_mfma_f32_16x16x32_bf16(
              af[fm], bfv[fn], acc[fm][fn], 0, 0, 0);
    }
  };

  // prologue: two tiles in flight (4*FR outstanding loads/wave)
  stage(0, 0);
  stage(1, 1);
  // main loop: wait until only the NEXT tile's 2*FR loads remain in flight
  for (int kt = 0; kt < nkt - 1; ++kt) {
    const int cur = kt & 1;
    waitcnt_vm<2 * FR>();
    __builtin_amdgcn_sched_barrier(0);
    __builtin_amdgcn_s_barrier();          // all waves: buf[cur] ready
    __builtin_amdgcn_sched_barrier(0);
    compute(cur);
    __builtin_amdgcn_sched_barrier(0);
    __builtin_amdgcn_s_barrier();          // all waves done reading buf[cur]
    __builtin_amdgcn_sched_barrier(0);
    if (kt + 2 < nkt) stage(kt + 2, cur);  // refill freed buffer
  }
  // peeled last tile: drain fully
  waitcnt_vm<0>();
  __builtin_amdgcn_sched_barrier(0);
  __builtin_amdgcn_s_barrier();
  __builtin_amdgcn_sched_barrier(0);
  compute((nkt - 1) & 1);

  const int rl = lane >> 4, cl = lane & 15;
  #pragma unroll
  for (int fm = 0; fm < FR; ++fm)
    #pragma unroll
    for (int fn = 0; fn < FR; ++fn)
      #pragma unroll
      for (int j = 0; j < 4; ++j) {
        int gm = m0 + wm * 16 * FR + fm * 16 + rl * 4 + j;
        int gn = n0 + wn * 16 * FR + fn * 16 + cl;
        if (gn < Nc) {
          float v = acc[fm][fn][j];
          if (EPI) v = fmaxf(v + bias[gn], 0.f);
          C[(size_t)gm * Nc + gn] = v;
        }
      }
}

// ---------------------------------------------------------------------------
// K3: blocks [0,1024) = per-triple attn+Weff+contraction+n2 (LDS/VALU-bound);
// blocks [1024,2048) = grid-stride entity_w fp32 -> bf16 padded cvt
// (HBM-bound). Fusing the two overlaps the ~30us cvt stream under the
// triple work instead of serializing it before the MLP.
// ---------------------------------------------------------------------------
__global__ __launch_bounds__(256, 2)
void triple_cvt(const int* __restrict__ heads, const int* __restrict__ rels,
                const int* __restrict__ tails, const float* __restrict__ ew,
                const float* __restrict__ rw, const float* __restrict__ wc,
                const float* __restrict__ hid, const float* __restrict__ w2,
                const float* __restrict__ b2, float* __restrict__ attn_out,
                unsigned short* __restrict__ x1b, float* __restrict__ n2,
                unsigned short* __restrict__ ewb) {
  __shared__ float hs[512], rs[512], ts[512];
  __shared__ __align__(16) float W123[4096][4];   // 64 KB
  __shared__ float att[8];
  __shared__ float wred[4][8];
  __shared__ float red[256];
  int tid = threadIdx.x;

  if (blockIdx.x >= NB) {
    // ---- entity_w fp32 -> bf16 (padded rows zeroed) ----
    const int n4valid = NE * DCOL / 4;        // 6,400,000
    const int n4tot = NE_PAD * DCOL / 4;      // 6,406,144
    int i = (blockIdx.x - NB) * 256 + tid;
    const int stride = 1024 * 256;
    for (; i < n4tot; i += stride) {
      float x = 0.f, y = 0.f, z = 0.f, w = 0.f;
      if (i < n4valid) {
        float4 v = ((const float4*)ew)[i];
        x = v.x; y = v.y; z = v.z; w = v.w;
      }
      union { unsigned short u[4]; uint2 v2; } o;
      o.u[0] = f2bf(x); o.u[1] = f2bf(y); o.u[2] = f2bf(z); o.u[3] = f2bf(w);
      ((uint2*)ewb)[i] = o.v2;
    }
    return;
  }

  int b = blockIdx.x;
  int lane = tid & 63, wid = tid >> 6;
  const float* hp_ = ew + (size_t)heads[b] * DCOL;
  const float* rp_ = rw + (size_t)rels[b] * DCOL;
  const float* tp_ = ew + (size_t)tails[b] * DCOL;
  float la[8] = {0, 0, 0, 0, 0, 0, 0, 0};
  #pragma unroll
  for (int it = 0; it < 2; ++it) {
    int d = it * 256 + tid;
    hs[d] = hp_[d]; rs[d] = rp_[d]; ts[d] = tp_[d];
    float hv = hid[(size_t)b * DCOL + d];
    #pragma unroll
    for (int c = 0; c < 8; ++c) la[c] = fmaf(hv, w2[d * 8 + c], la[c]);
  }
  // attention: wave reduce then cross-wave + softmax
  #pragma unroll
  for (int off = 32; off > 0; off >>= 1)
    #pragma unroll
    for (int c = 0; c < 8; ++c) la[c] += __shfl_down(la[c], off);
  if (lane == 0)
    #pragma unroll
    for (int c = 0; c < 8; ++c) wred[wid][c] = la[c];
  __syncthreads();
  if (tid == 0) {
    float lg[8];
    #pragma unroll
    for (int c = 0; c < 8; ++c)
      lg[c] = wred[0][c] + wred[1][c] + wred[2][c] + wred[3][c] + b2[c];
    float mx = lg[0];
    #pragma unroll
    for (int c = 1; c < 8; ++c) mx = fmaxf(mx, lg[c]);
    float e[8], s = 0.f;
    #pragma unroll
    for (int c = 0; c < 8; ++c) { e[c] = expf(lg[c] - mx); s += e[c]; }
    #pragma unroll
    for (int c = 0; c < 8; ++c) {
      float a = e[c] / s;
      att[c] = a;
      attn_out[(size_t)b * 8 + c] = a;
    }
  }
  __syncthreads();
  #pragma unroll
  for (int it = 0; it < 16; ++it) {
    int idx = it * 256 + tid;
    float w = 0.f;
    #pragma unroll
    for (int c = 0; c < 8; ++c) w = fmaf(att[c], wc[c * 4096 + idx], w);
    int s = idx & 15, q = (idx >> 4) & 15, p = idx >> 8;
    W123[idx][0] = w;                     // [p][q][s]
    W123[(q * 16 + s) * 16 + p][1] = w;   // [q][s][p]
    W123[(p * 16 + s) * 16 + q][2] = w;   // [p][s][q]
  }
  __syncthreads();

  const int so = tid & 15;
  const int i0 = tid >> 4, i1 = i0 + 16;
  float h0[16], r0[16], t0[16], h1[16], r1[16], t1[16];
  #pragma unroll
  for (int k = 0; k < 16; ++k) {
    h0[k] = hs[i0 * 16 + k]; r0[k] = rs[i0 * 16 + k]; t0[k] = ts[i0 * 16 + k];
    h1[k] = hs[i1 * 16 + k]; r1[k] = rs[i1 * 16 + k]; t1[k] = ts[i1 * 16 + k];
  }
  float a10 = 0.f, a20 = 0.f, a30 = 0.f, a11 = 0.f, a21 = 0.f, a31 = 0.f;
  const float4* wp = (const float4*)&W123[so][0];   // per-thread base
  #pragma unroll
  for (int u = 0; u < 16; ++u) {
    #pragma unroll
    for (int v = 0; v < 16; ++v) {
      float4 w = wp[u * 256 + v * 16];   // byte off = u*4096+v*256 (imm)
      a10 = fmaf(h0[u] * r0[v], w.x, a10);
      a20 = fmaf(r0[u] * t0[v], w.y, a20);
      a30 = fmaf(h0[u] * t0[v], w.z, a30);
      a11 = fmaf(h1[u] * r1[v], w.x, a11);
      a21 = fmaf(r1[u] * t1[v], w.y, a21);
      a31 = fmaf(h1[u] * t1[v], w.z, a31);
    }
  }
  x1b[(size_t)b * 512 + i0 * 16 + so] = f2bf(a10);
  x1b[(size_t)b * 512 + i1 * 16 + so] = f2bf(a11);
  red[tid] = a10 * a10 + a20 * a20 + a30 * a30
           + a11 * a11 + a21 * a21 + a31 * a31;
  __syncthreads();
  for (int s = 128; s > 0; s >>= 1) {
    if (tid < s) red[tid] += red[tid + s];
    __syncthreads();
  }
  if (tid == 0) n2[b] = red[0];
}

// ---------------------------------------------------------------------------
// K5: factors. factor1 = sum(n1)/B; factor2 = sum(n2)/B; factor3 geometric.
// ---------------------------------------------------------------------------
__global__ __launch_bounds__(256)
void finalize(const float* __restrict__ n1, const float* __restrict__ n2,
              const float* __restrict__ wc, float* __restrict__ out) {
  int tid = threadIdx.x;
  __shared__ float red[256];
  float a = 0.f;
  for (int i = tid; i < NB; i += 256) a += n1[i];
  red[tid] = a; __syncthreads();
  for (int s = 128; s > 0; s >>= 1) { if (tid < s) red[tid] += red[tid + s]; __syncthreads(); }
  if (tid == 0) out[F1_OFF] = red[0] / (float)NB;
  __syncthreads();
  a = 0.f;
  for (int i = tid; i < NB; i += 256) a += n2[i];
  red[tid] = a; __syncthreads();
  for (int s = 128; s > 0; s >>= 1) { if (tid < s) red[tid] += red[tid + s]; __syncthreads(); }
  if (tid == 0) out[F2_OFF] = red[0] / (float)NB;
  __syncthreads();

  // factor3: 32 lanes per core
  int c = tid >> 5, l = tid & 31;
  float tot = 0.f, cx = 0.f, cy = 0.f, cz = 0.f;
  for (int e = l; e < 4096; e += 32) {
    float w = fabsf(wc[c * 4096 + e]);
    int z = e & 15, y = (e >> 4) & 15, x = e >> 8;
    tot += w; cx += w * x; cy += w * y; cz += w * z;
  }
  #pragma unroll
  for (int off = 16; off > 0; off >>= 1) {
    tot += __shfl_down(tot, off);
    cx += __shfl_down(cx, off);
    cy += __shfl_down(cy, off);
    cz += __shfl_down(cz, off);
  }
  __shared__ float cent[8][3];
  if (l == 0) { cent[c][0] = cx / tot; cent[c][1] = cy / tot; cent[c][2] = cz / tot; }
  __syncthreads();
  if (tid == 0) {
    float f3 = 0.f;
    for (int i = 0; i < 8; ++i) {
      float mn = 1e30f;
      for (int j = 0; j < 8; ++j) {
        if (j == i) continue;
        float dx = cent[i][0] - cent[j][0];
        float dy = cent[i][1] - cent[j][1];
        float dz = cent[i][2] - cent[j][2];
        float d = sqrtf(dx * dx + dy * dy + dz * dz);
        mn = fminf(mn, d);
      }
      f3 += logf(mn + 1e-6f);
    }
    out[F3_OFF] = -f3 / 8.f;
  }
}

// ---------------------------------------------------------------------------
extern "C" void kernel_launch(void* const* d_in, const int* in_sizes, int n_in,
                              void* d_out, int out_size, void* d_ws, size_t ws_size,
                              hipStream_t stream) {
  const int* heads = (const int*)d_in[0];
  const int* rels = (const int*)d_in[1];
  const int* tails = (const int*)d_in[2];
  const float* ew = (const float*)d_in[3];
  const float* rw = (const float*)d_in[4];
  const float* wc = (const float*)d_in[5];
  const float* w1 = (const float*)d_in[6];
  const float* b1 = (const float*)d_in[7];
  const float* w2 = (const float*)d_in[8];
  const float* b2 = (const float*)d_in[9];
  float* out = (float*)d_out;

  uint8_t* ws = (uint8_t*)d_ws;
  const size_t EWB_SZ = (size_t)NE_PAD * DCOL * 2;   // 51,249,152
  unsigned short* ewb = (unsigned short*)ws;
  unsigned short* hrb = (unsigned short*)(ws + EWB_SZ);
  unsigned short* w1t = (unsigned short*)(ws + EWB_SZ + 2097152);
  float* hid = (float*)(ws + EWB_SZ + 2097152 + 1048576);
  unsigned short* x1b = (unsigned short*)(ws + EWB_SZ + 2097152 + 1048576 + 2097152);
  float* n1 = (float*)(ws + EWB_SZ + 2097152 + 1048576 + 2097152 + 1048576);
  float* n2 = n1 + NB;

  prep<<<NB + 512, 256, 0, stream>>>(heads, rels, tails, ew, rw, w1,
                                     hrb, w1t, n1);
  // MLP GEMM: M=1024 (MT=16, BM=64), N=512 (NT=8), K=1024
  gemm_nt<1, 2, 0, 16><<<128, 256, 0, stream>>>(
      hrb, w1t, hid, b1, 1024, 512, 8);
  // triple contraction (blocks 0..1023) + entity_w cvt (blocks 1024..2047)
  triple_cvt<<<2 * NB, 256, 0, stream>>>(heads, rels, tails, ew, rw, wc,
                                         hid, w2, b2, out + ATTN_OFF, x1b, n2,
                                         ewb);
  // scores GEMM: M=1024 (MT=8, BM=128), N-tiles=391, K=512, bf16 B
  gemm_nt<0, 4, 1, 8><<<3128, 256, 0, stream>>>(
      x1b, ewb, out, nullptr, 512, NE, 391);
  finalize<<<1, 256, 0, stream>>>(n1, n2, wc, out);
}

// Round 12
// 215.249 us; speedup vs baseline: 1.1186x; 1.1186x over previous
//
#include <hip/hip_runtime.h>
#include <cstdint>
#include <cstddef>

// Problem constants
#define NB 1024        // batch of triples
#define NE 50000       // entities
#define NE_PAD 50048   // padded to 391*128
#define DCOL 512       // dimension D
#define ATTN_C 8       // cores

static const size_t SCORES_OFF = (size_t)NB * NE;        // 51,200,000
static const size_t F1_OFF = SCORES_OFF + 0;
static const size_t F2_OFF = SCORES_OFF + 1;
static const size_t F3_OFF = SCORES_OFF + 2;
static const size_t ATTN_OFF = SCORES_OFF + 3;

typedef float f32x4 __attribute__((ext_vector_type(4)));
typedef short s16x8 __attribute__((ext_vector_type(8)));

__device__ __forceinline__ unsigned short f2bf(float f) {
  union { float f; uint32_t u; } x; x.f = f;
  uint32_t u = x.u;
  uint32_t r = (u + 0x7fffu + ((u >> 16) & 1u)) >> 16;  // RNE
  return (unsigned short)r;
}

__device__ __forceinline__ void gload16(const void* g, void* l) {
  __builtin_amdgcn_global_load_lds(
      (const __attribute__((address_space(1))) uint32_t*)g,
      (__attribute__((address_space(3))) uint32_t*)l, 16, 0, 0);
}

// counted vmcnt wait — N derived from template (loads-per-stage); R6 lesson:
// a too-large N is a no-op wait -> races.
template <int N>
__device__ __forceinline__ void waitcnt_vm() {
  static_assert(N == 0 || N == 4 || N == 8, "literal dispatch");
  if constexpr (N == 0) asm volatile("s_waitcnt vmcnt(0)" ::: "memory");
  else if constexpr (N == 4) asm volatile("s_waitcnt vmcnt(4)" ::: "memory");
  else if constexpr (N == 8) asm volatile("s_waitcnt vmcnt(8)" ::: "memory");
}

// ---------------------------------------------------------------------------
// K1 (fused prep, R7-proven): blocks [0,1024) = gather h,r -> HR bf16 + n1;
// blocks [1024,1536) = transpose W1 -> bf16; blocks [1536,3584) = grid-stride
// entity_w fp32 -> bf16 padded. (R11 lesson: keep the cvt in this LOW-LDS
// kernel — fusing it into the 73KB-LDS triple kernel throttled it to 2
// blocks/CU and regressed 29us.)
// ---------------------------------------------------------------------------
__global__ __launch_bounds__(256)
void prep(const int* __restrict__ heads, const int* __restrict__ rels,
          const int* __restrict__ tails, const float* __restrict__ ew,
          const float* __restrict__ rw, const float* __restrict__ w1,
          unsigned short* __restrict__ hrb, unsigned short* __restrict__ w1t,
          unsigned short* __restrict__ ewb, float* __restrict__ n1) {
  int tid = threadIdx.x;
  if (blockIdx.x < NB) {
    int b = blockIdx.x;
    const float* h = ew + (size_t)heads[b] * DCOL;
    const float* r = rw + (size_t)rels[b] * DCOL;
    const float* t = ew + (size_t)tails[b] * DCOL;
    float acc = 0.f;
    #pragma unroll
    for (int it = 0; it < 2; ++it) {
      int d = it * 256 + tid;
      float hv = h[d], rv = r[d], tv = t[d];
      hrb[(size_t)b * 1024 + d] = f2bf(hv);
      hrb[(size_t)b * 1024 + DCOL + d] = f2bf(rv);
      acc += hv * hv + rv * rv + tv * tv;
    }
    __shared__ float red[256];
    red[tid] = acc; __syncthreads();
    for (int s = 128; s > 0; s >>= 1) {
      if (tid < s) red[tid] += red[tid + s];
      __syncthreads();
    }
    if (tid == 0) n1[b] = red[0];
  } else if (blockIdx.x < NB + 512) {
    int tb = blockIdx.x - NB;          // 0..511
    int nb = (tb & 15) * 32, kb = (tb >> 4) * 32;
    __shared__ float tile[32][33];
    int tx = tid & 31, ty = tid >> 5;  // ty 0..7
    #pragma unroll
    for (int rr = 0; rr < 32; rr += 8)
      tile[ty + rr][tx] = w1[(size_t)(kb + ty + rr) * 512 + nb + tx];
    __syncthreads();
    #pragma unroll
    for (int rr = 0; rr < 32; rr += 8)
      w1t[(size_t)(nb + ty + rr) * 1024 + kb + tx] = f2bf(tile[tx][ty + rr]);
  } else {
    const int n4valid = NE * DCOL / 4;        // 6,400,000
    const int n4tot = NE_PAD * DCOL / 4;      // 6,406,144
    int i = (blockIdx.x - NB - 512) * 256 + tid;
    const int stride = 2048 * 256;
    for (; i < n4tot; i += stride) {
      float x = 0.f, y = 0.f, z = 0.f, w = 0.f;
      if (i < n4valid) {
        float4 v = ((const float4*)ew)[i];
        x = v.x; y = v.y; z = v.z; w = v.w;
      }
      union { unsigned short u[4]; uint2 v2; } o;
      o.u[0] = f2bf(x); o.u[1] = f2bf(y); o.u[2] = f2bf(z); o.u[3] = f2bf(w);
      ((uint2*)ewb)[i] = o.v2;
    }
  }
}

// ---------------------------------------------------------------------------
// K2/K4: NT GEMM bf16 -> fp32, R7 handshake, generalized wave geometry.
// WM x WN waves (NW*64 threads), per-wave output (16*FRm) x (16*FRn),
// tile BM = WM*16*FRm rows x BN = WN*16*FRn cols, BK=64.
// Operands via global_load_lds (width 16) with XOR-chunk source swizzle.
// Counted-vmcnt pipeline: raw s_barrier + s_waitcnt vmcnt(SOPS) where
// SOPS = CPW_A + CPW_B (chunks per wave per stage, template-derived).
// R5->R11 counters showed the 4-wave config is latency-bound at 2 waves/SIMD
// (MfmaUtil 13%, Occ 20%): the 8-wave (512-thread) scores config doubles
// waves/SIMD to 4 at identical LDS (64KB, 2 blocks/CU) for pure TLP.
// SWZ=1: XCD-ownership swizzle (bijective, MT*NT%8==0) -> each B-tile in
// exactly one per-XCD L2 (FETCH 403->71MB, R5).
// ---------------------------------------------------------------------------
template <int EPI, int WM, int WN, int FRm, int FRn, int SWZ, int MT>
__global__ __launch_bounds__(WM * WN * 64, WM * WN == 8 ? 4 : 2)
void gemm_nt(const unsigned short* __restrict__ A,
             const unsigned short* __restrict__ B,
             float* __restrict__ C, const float* __restrict__ bias,
             int K, int Nc, int NT) {
  constexpr int NW = WM * WN;
  constexpr int BM = WM * 16 * FRm;      // tile rows (A)
  constexpr int BN = WN * 16 * FRn;      // tile cols (B rows)
  constexpr int TILE_A = BM * 128;       // bytes (BK=64 bf16)
  constexpr int TILE_B = BN * 128;
  constexpr int BUFSZ = TILE_A + TILE_B;
  constexpr int CPW_A = (BM / 8) / NW;   // A chunks per wave per stage
  constexpr int CPW_B = (BN / 8) / NW;
  constexpr int SOPS = CPW_A + CPW_B;    // vmcnt ops per stage per wave
  static_assert((BM / 8) % NW == 0 && (BN / 8) % NW == 0, "chunk split");
  __shared__ __align__(16) uint8_t smem[2 * BUFSZ];
  const int tid = threadIdx.x;
  const int lane = tid & 63;
  const int wv = tid >> 6;
  const int wm = wv / WN, wn = wv % WN;

  int m_t, n_t;
  if (SWZ) {
    int xcd = blockIdx.x & 7;
    int l = blockIdx.x >> 3;
    int w = xcd * ((MT * NT) >> 3) + l;  // bijective: MT*NT % 8 == 0
    n_t = w / MT; m_t = w % MT;
  } else {
    m_t = blockIdx.x % MT; n_t = blockIdx.x / MT;
  }
  const int m0 = m_t * BM;
  const int n0 = n_t * BN;
  const int rbytes = K * 2;

  f32x4 acc[FRm][FRn];
  #pragma unroll
  for (int i = 0; i < FRm; ++i)
    #pragma unroll
    for (int j = 0; j < FRn; ++j) acc[i][j] = (f32x4){0.f, 0.f, 0.f, 0.f};

  const int srow = lane >> 3;   // row within 8-row chunk
  const int scol = lane & 7;    // dest 16B unit within row
  const int nkt = K >> 6;       // K / 64

  auto stage = [&](int kt, int buf) {
    #pragma unroll
    for (int j = 0; j < CPW_A; ++j) {
      const int chunk = wv * CPW_A + j;
      const int r = chunk * 8 + srow;
      const int c = scol ^ (r & 7);
      gload16((const uint8_t*)A + (size_t)(m0 + r) * rbytes + kt * 128 + c * 16,
              &smem[buf * BUFSZ + chunk * 1024]);
    }
    #pragma unroll
    for (int j = 0; j < CPW_B; ++j) {
      const int chunk = wv * CPW_B + j;
      const int r = chunk * 8 + srow;
      const int c = scol ^ (r & 7);
      gload16((const uint8_t*)B + (size_t)(n0 + r) * rbytes + kt * 128 + c * 16,
              &smem[buf * BUFSZ + TILE_A + chunk * 1024]);
    }
  };
  auto compute = [&](int buf) {
    const uint8_t* sa = &smem[buf * BUFSZ];
    const uint8_t* sb = sa + TILE_A;
    #pragma unroll
    for (int kk = 0; kk < 2; ++kk) {
      s16x8 af[FRm], bfv[FRn];
      #pragma unroll
      for (int f = 0; f < FRm; ++f) {
        const int ra = (wm * FRm + f) * 16 + (lane & 15);
        const int ca = (kk * 4 + (lane >> 4)) ^ (ra & 7);
        af[f] = *(const s16x8*)&sa[ra * 128 + ca * 16];
      }
      #pragma unroll
      for (int f = 0; f < FRn; ++f) {
        const int rb = (wn * FRn + f) * 16 + (lane & 15);
        const int cb = (kk * 4 + (lane >> 4)) ^ (rb & 7);
        bfv[f] = *(const s16x8*)&sb[rb * 128 + cb * 16];
      }
      #pragma unroll
      for (int fm = 0; fm < FRm; ++fm)
        #pragma unroll
        for (int fn = 0; fn < FRn; ++fn)
          acc[fm][fn] = __builtin_amdgcn_mfma_f32_16x16x32_bf16(
              af[fm], bfv[fn], acc[fm][fn], 0, 0, 0);
    }
  };

  // prologue: two tiles in flight (2*SOPS outstanding loads/wave)
  stage(0, 0);
  stage(1, 1);
  // main loop: wait until only the NEXT tile's SOPS loads remain in flight
  for (int kt = 0; kt < nkt - 1; ++kt) {
    const int cur = kt & 1;
    waitcnt_vm<SOPS>();
    __builtin_amdgcn_sched_barrier(0);
    __builtin_amdgcn_s_barrier();          // all waves: buf[cur] ready
    __builtin_amdgcn_sched_barrier(0);
    compute(cur);
    __builtin_amdgcn_sched_barrier(0);
    __builtin_amdgcn_s_barrier();          // all waves done reading buf[cur]
    __builtin_amdgcn_sched_barrier(0);
    if (kt + 2 < nkt) stage(kt + 2, cur);  // refill freed buffer
  }
  // peeled last tile: drain fully
  waitcnt_vm<0>();
  __builtin_amdgcn_sched_barrier(0);
  __builtin_amdgcn_s_barrier();
  __builtin_amdgcn_sched_barrier(0);
  compute((nkt - 1) & 1);

  const int rl = lane >> 4, cl = lane & 15;
  #pragma unroll
  for (int fm = 0; fm < FRm; ++fm)
    #pragma unroll
    for (int fn = 0; fn < FRn; ++fn)
      #pragma unroll
      for (int j = 0; j < 4; ++j) {
        int gm = m0 + (wm * FRm + fm) * 16 + rl * 4 + j;
        int gn = n0 + (wn * FRn + fn) * 16 + cl;
        if (gn < Nc) {
          float v = acc[fm][fn][j];
          if (EPI) v = fmaxf(v + bias[gn], 0.f);
          C[(size_t)gm * Nc + gn] = v;
        }
      }
}

// ---------------------------------------------------------------------------
// K3: per-triple: attn logits+softmax (fused), Weff, contraction, n2.
// (R7-proven standalone version.)
// ---------------------------------------------------------------------------
__global__ __launch_bounds__(256, 2)
void triple_core(const int* __restrict__ heads, const int* __restrict__ rels,
                 const int* __restrict__ tails, const float* __restrict__ ew,
                 const float* __restrict__ rw, const float* __restrict__ wc,
                 const float* __restrict__ hid, const float* __restrict__ w2,
                 const float* __restrict__ b2, float* __restrict__ attn_out,
                 unsigned short* __restrict__ x1b, float* __restrict__ n2) {
  __shared__ float hs[512], rs[512], ts[512];
  __shared__ __align__(16) float W123[4096][4];   // 64 KB
  __shared__ float att[8];
  __shared__ float wred[4][8];
  __shared__ float red[256];
  int b = blockIdx.x, tid = threadIdx.x;
  int lane = tid & 63, wid = tid >> 6;
  const float* hp_ = ew + (size_t)heads[b] * DCOL;
  const float* rp_ = rw + (size_t)rels[b] * DCOL;
  const float* tp_ = ew + (size_t)tails[b] * DCOL;
  float la[8] = {0, 0, 0, 0, 0, 0, 0, 0};
  #pragma unroll
  for (int it = 0; it < 2; ++it) {
    int d = it * 256 + tid;
    hs[d] = hp_[d]; rs[d] = rp_[d]; ts[d] = tp_[d];
    float hv = hid[(size_t)b * DCOL + d];
    #pragma unroll
    for (int c = 0; c < 8; ++c) la[c] = fmaf(hv, w2[d * 8 + c], la[c]);
  }
  #pragma unroll
  for (int off = 32; off > 0; off >>= 1)
    #pragma unroll
    for (int c = 0; c < 8; ++c) la[c] += __shfl_down(la[c], off);
  if (lane == 0)
    #pragma unroll
    for (int c = 0; c < 8; ++c) wred[wid][c] = la[c];
  __syncthreads();
  if (tid == 0) {
    float lg[8];
    #pragma unroll
    for (int c = 0; c < 8; ++c)
      lg[c] = wred[0][c] + wred[1][c] + wred[2][c] + wred[3][c] + b2[c];
    float mx = lg[0];
    #pragma unroll
    for (int c = 1; c < 8; ++c) mx = fmaxf(mx, lg[c]);
    float e[8], s = 0.f;
    #pragma unroll
    for (int c = 0; c < 8; ++c) { e[c] = expf(lg[c] - mx); s += e[c]; }
    #pragma unroll
    for (int c = 0; c < 8; ++c) {
      float a = e[c] / s;
      att[c] = a;
      attn_out[(size_t)b * 8 + c] = a;
    }
  }
  __syncthreads();
  #pragma unroll
  for (int it = 0; it < 16; ++it) {
    int idx = it * 256 + tid;
    float w = 0.f;
    #pragma unroll
    for (int c = 0; c < 8; ++c) w = fmaf(att[c], wc[c * 4096 + idx], w);
    int s = idx & 15, q = (idx >> 4) & 15, p = idx >> 8;
    W123[idx][0] = w;                     // [p][q][s]
    W123[(q * 16 + s) * 16 + p][1] = w;   // [q][s][p]
    W123[(p * 16 + s) * 16 + q][2] = w;   // [p][s][q]
  }
  __syncthreads();

  const int so = tid & 15;
  const int i0 = tid >> 4, i1 = i0 + 16;
  float h0[16], r0[16], t0[16], h1[16], r1[16], t1[16];
  #pragma unroll
  for (int k = 0; k < 16; ++k) {
    h0[k] = hs[i0 * 16 + k]; r0[k] = rs[i0 * 16 + k]; t0[k] = ts[i0 * 16 + k];
    h1[k] = hs[i1 * 16 + k]; r1[k] = rs[i1 * 16 + k]; t1[k] = ts[i1 * 16 + k];
  }
  float a10 = 0.f, a20 = 0.f, a30 = 0.f, a11 = 0.f, a21 = 0.f, a31 = 0.f;
  const float4* wp = (const float4*)&W123[so][0];   // per-thread base
  #pragma unroll
  for (int u = 0; u < 16; ++u) {
    #pragma unroll
    for (int v = 0; v < 16; ++v) {
      float4 w = wp[u * 256 + v * 16];   // byte off = u*4096+v*256 (imm)
      a10 = fmaf(h0[u] * r0[v], w.x, a10);
      a20 = fmaf(r0[u] * t0[v], w.y, a20);
      a30 = fmaf(h0[u] * t0[v], w.z, a30);
      a11 = fmaf(h1[u] * r1[v], w.x, a11);
      a21 = fmaf(r1[u] * t1[v], w.y, a21);
      a31 = fmaf(h1[u] * t1[v], w.z, a31);
    }
  }
  x1b[(size_t)b * 512 + i0 * 16 + so] = f2bf(a10);
  x1b[(size_t)b * 512 + i1 * 16 + so] = f2bf(a11);
  red[tid] = a10 * a10 + a20 * a20 + a30 * a30
           + a11 * a11 + a21 * a21 + a31 * a31;
  __syncthreads();
  for (int s = 128; s > 0; s >>= 1) {
    if (tid < s) red[tid] += red[tid + s];
    __syncthreads();
  }
  if (tid == 0) n2[b] = red[0];
}

// ---------------------------------------------------------------------------
// K5: factors. factor1 = sum(n1)/B; factor2 = sum(n2)/B; factor3 geometric.
// ---------------------------------------------------------------------------
__global__ __launch_bounds__(256)
void finalize(const float* __restrict__ n1, const float* __restrict__ n2,
              const float* __restrict__ wc, float* __restrict__ out) {
  int tid = threadIdx.x;
  __shared__ float red[256];
  float a = 0.f;
  for (int i = tid; i < NB; i += 256) a += n1[i];
  red[tid] = a; __syncthreads();
  for (int s = 128; s > 0; s >>= 1) { if (tid < s) red[tid] += red[tid + s]; __syncthreads(); }
  if (tid == 0) out[F1_OFF] = red[0] / (float)NB;
  __syncthreads();
  a = 0.f;
  for (int i = tid; i < NB; i += 256) a += n2[i];
  red[tid] = a; __syncthreads();
  for (int s = 128; s > 0; s >>= 1) { if (tid < s) red[tid] += red[tid + s]; __syncthreads(); }
  if (tid == 0) out[F2_OFF] = red[0] / (float)NB;
  __syncthreads();

  int c = tid >> 5, l = tid & 31;
  float tot = 0.f, cx = 0.f, cy = 0.f, cz = 0.f;
  for (int e = l; e < 4096; e += 32) {
    float w = fabsf(wc[c * 4096 + e]);
    int z = e & 15, y = (e >> 4) & 15, x = e >> 8;
    tot += w; cx += w * x; cy += w * y; cz += w * z;
  }
  #pragma unroll
  for (int off = 16; off > 0; off >>= 1) {
    tot += __shfl_down(tot, off);
    cx += __shfl_down(cx, off);
    cy += __shfl_down(cy, off);
    cz += __shfl_down(cz, off);
  }
  __shared__ float cent[8][3];
  if (l == 0) { cent[c][0] = cx / tot; cent[c][1] = cy / tot; cent[c][2] = cz / tot; }
  __syncthreads();
  if (tid == 0) {
    float f3 = 0.f;
    for (int i = 0; i < 8; ++i) {
      float mn = 1e30f;
      for (int j = 0; j < 8; ++j) {
        if (j == i) continue;
        float dx = cent[i][0] - cent[j][0];
        float dy = cent[i][1] - cent[j][1];
        float dz = cent[i][2] - cent[j][2];
        float d = sqrtf(dx * dx + dy * dy + dz * dz);
        mn = fminf(mn, d);
      }
      f3 += logf(mn + 1e-6f);
    }
    out[F3_OFF] = -f3 / 8.f;
  }
}

// ---------------------------------------------------------------------------
extern "C" void kernel_launch(void* const* d_in, const int* in_sizes, int n_in,
                              void* d_out, int out_size, void* d_ws, size_t ws_size,
                              hipStream_t stream) {
  const int* heads = (const int*)d_in[0];
  const int* rels = (const int*)d_in[1];
  const int* tails = (const int*)d_in[2];
  const float* ew = (const float*)d_in[3];
  const float* rw = (const float*)d_in[4];
  const float* wc = (const float*)d_in[5];
  const float* w1 = (const float*)d_in[6];
  const float* b1 = (const float*)d_in[7];
  const float* w2 = (const float*)d_in[8];
  const float* b2 = (const float*)d_in[9];
  float* out = (float*)d_out;

  uint8_t* ws = (uint8_t*)d_ws;
  const size_t EWB_SZ = (size_t)NE_PAD * DCOL * 2;   // 51,249,152
  unsigned short* ewb = (unsigned short*)ws;
  unsigned short* hrb = (unsigned short*)(ws + EWB_SZ);
  unsigned short* w1t = (unsigned short*)(ws + EWB_SZ + 2097152);
  float* hid = (float*)(ws + EWB_SZ + 2097152 + 1048576);
  unsigned short* x1b = (unsigned short*)(ws + EWB_SZ + 2097152 + 1048576 + 2097152);
  float* n1 = (float*)(ws + EWB_SZ + 2097152 + 1048576 + 2097152 + 1048576);
  float* n2 = n1 + NB;

  prep<<<NB + 512 + 2048, 256, 0, stream>>>(heads, rels, tails, ew, rw, w1,
                                            hrb, w1t, ewb, n1);
  // MLP GEMM: 64x64 tiles (2x2 waves, FR 2x2), MT=16, NT=8, K=1024
  gemm_nt<1, 2, 2, 2, 2, 0, 16><<<128, 256, 0, stream>>>(
      hrb, w1t, hid, b1, 1024, 512, 8);
  triple_core<<<NB, 256, 0, stream>>>(heads, rels, tails, ew, rw, wc,
                                      hid, w2, b2, out + ATTN_OFF, x1b, n2);
  // scores GEMM: 128x128 tiles, 8 waves (2x4, FR 4x2), MT=8, NT=391, K=512
  gemm_nt<0, 2, 4, 4, 2, 1, 8><<<3128, 512, 0, stream>>>(
      x1b, ewb, out, nullptr, 512, NE, 391);
  finalize<<<1, 256, 0, stream>>>(n1, n2, wc, out);
}

// Round 13
// 214.762 us; speedup vs baseline: 1.1211x; 1.0023x over previous
//
#include <hip/hip_runtime.h>
#include <cstdint>
#include <cstddef>

// Problem constants
#define NB 1024        // batch of triples
#define NE 50000       // entities
#define NE_PAD 50048   // padded to 391*128
#define DCOL 512       // dimension D
#define ATTN_C 8       // cores

static const size_t SCORES_OFF = (size_t)NB * NE;        // 51,200,000
static const size_t F1_OFF = SCORES_OFF + 0;
static const size_t F2_OFF = SCORES_OFF + 1;
static const size_t F3_OFF = SCORES_OFF + 2;
static const size_t ATTN_OFF = SCORES_OFF + 3;

typedef float f32x4 __attribute__((ext_vector_type(4)));
typedef short s16x8 __attribute__((ext_vector_type(8)));

__device__ __forceinline__ unsigned short f2bf(float f) {
  union { float f; uint32_t u; } x; x.f = f;
  uint32_t u = x.u;
  uint32_t r = (u + 0x7fffu + ((u >> 16) & 1u)) >> 16;  // RNE
  return (unsigned short)r;
}

__device__ __forceinline__ void gload16(const void* g, void* l) {
  __builtin_amdgcn_global_load_lds(
      (const __attribute__((address_space(1))) uint32_t*)g,
      (__attribute__((address_space(3))) uint32_t*)l, 16, 0, 0);
}

// counted vmcnt wait — N derived from template (loads-per-stage); R6 lesson:
// a too-large N is a no-op wait -> races.
template <int N>
__device__ __forceinline__ void waitcnt_vm() {
  static_assert(N == 0 || N == 4 || N == 8, "literal dispatch");
  if constexpr (N == 0) asm volatile("s_waitcnt vmcnt(0)" ::: "memory");
  else if constexpr (N == 4) asm volatile("s_waitcnt vmcnt(4)" ::: "memory");
  else if constexpr (N == 8) asm volatile("s_waitcnt vmcnt(8)" ::: "memory");
}

// ---------------------------------------------------------------------------
// K1 prep (small): blocks [0,1024) = gather h,r -> HR bf16 + n1;
// blocks [1024,1536) = transpose W1 -> bf16.
// The entity_w->bf16 cvt lives in the MLP GEMM dispatch (32KB-LDS kernel ->
// cvt blocks get 5 blocks/CU; R11 showed the 73KB triple kernel throttles
// it; as a serial prep pass it wastes ~40us of pure HBM streaming).
// ---------------------------------------------------------------------------
__global__ __launch_bounds__(256)
void prep(const int* __restrict__ heads, const int* __restrict__ rels,
          const int* __restrict__ tails, const float* __restrict__ ew,
          const float* __restrict__ rw, const float* __restrict__ w1,
          unsigned short* __restrict__ hrb, unsigned short* __restrict__ w1t,
          float* __restrict__ n1) {
  int tid = threadIdx.x;
  if (blockIdx.x < NB) {
    int b = blockIdx.x;
    const float* h = ew + (size_t)heads[b] * DCOL;
    const float* r = rw + (size_t)rels[b] * DCOL;
    const float* t = ew + (size_t)tails[b] * DCOL;
    float acc = 0.f;
    #pragma unroll
    for (int it = 0; it < 2; ++it) {
      int d = it * 256 + tid;
      float hv = h[d], rv = r[d], tv = t[d];
      hrb[(size_t)b * 1024 + d] = f2bf(hv);
      hrb[(size_t)b * 1024 + DCOL + d] = f2bf(rv);
      acc += hv * hv + rv * rv + tv * tv;
    }
    __shared__ float red[256];
    red[tid] = acc; __syncthreads();
    for (int s = 128; s > 0; s >>= 1) {
      if (tid < s) red[tid] += red[tid + s];
      __syncthreads();
    }
    if (tid == 0) n1[b] = red[0];
  } else {
    int tb = blockIdx.x - NB;          // 0..511
    int nb = (tb & 15) * 32, kb = (tb >> 4) * 32;
    __shared__ float tile[32][33];
    int tx = tid & 31, ty = tid >> 5;  // ty 0..7
    #pragma unroll
    for (int rr = 0; rr < 32; rr += 8)
      tile[ty + rr][tx] = w1[(size_t)(kb + ty + rr) * 512 + nb + tx];
    __syncthreads();
    #pragma unroll
    for (int rr = 0; rr < 32; rr += 8)
      w1t[(size_t)(nb + ty + rr) * 1024 + kb + tx] = f2bf(tile[tx][ty + rr]);
  }
}

// ---------------------------------------------------------------------------
// K2/K4: NT GEMM bf16 -> fp32, R7 handshake, generalized wave geometry.
// WM x WN waves (NW*64 threads), per-wave output (16*FRm) x (16*FRn),
// tile BM = WM*16*FRm rows x BN = WN*16*FRn cols, BK=64.
// Operands via global_load_lds (width 16) with XOR-chunk source swizzle.
// Counted-vmcnt pipeline: raw s_barrier + s_waitcnt vmcnt(SOPS) where
// SOPS = CPW_A + CPW_B (chunks per wave per stage, template-derived).
// Scores uses the PROVEN 4-wave (2x2, FR 4x4) config: R12's 8-wave A/B was
// neutral -> not TLP-bound; the 2-barrier structure's per-phase overhead is
// the binding constraint (m233), so keep the simplest proven form.
// SWZ=1: XCD-ownership swizzle (bijective, MT*NT%8==0).
// CVT=1: blocks >= ngemm run grid-stride entity_w fp32 -> bf16 padded cvt
// (overlaps the 256MB stream with the GEMM on otherwise-idle CUs).
// ---------------------------------------------------------------------------
template <int EPI, int WM, int WN, int FRm, int FRn, int SWZ, int MT, int CVT>
__global__ __launch_bounds__(WM * WN * 64, 2)
void gemm_nt(const unsigned short* __restrict__ A,
             const unsigned short* __restrict__ B,
             float* __restrict__ C, const float* __restrict__ bias,
             int K, int Nc, int NT,
             const float* __restrict__ cvt_src,
             unsigned short* __restrict__ cvt_dst, int ngemm) {
  constexpr int NW = WM * WN;
  constexpr int BM = WM * 16 * FRm;      // tile rows (A)
  constexpr int BN = WN * 16 * FRn;      // tile cols (B rows)
  constexpr int TILE_A = BM * 128;       // bytes (BK=64 bf16)
  constexpr int TILE_B = BN * 128;
  constexpr int BUFSZ = TILE_A + TILE_B;
  constexpr int CPW_A = (BM / 8) / NW;   // A chunks per wave per stage
  constexpr int CPW_B = (BN / 8) / NW;
  constexpr int SOPS = CPW_A + CPW_B;    // vmcnt ops per stage per wave
  static_assert((BM / 8) % NW == 0 && (BN / 8) % NW == 0, "chunk split");
  __shared__ __align__(16) uint8_t smem[2 * BUFSZ];
  const int tid = threadIdx.x;

  if (CVT && (int)blockIdx.x >= ngemm) {
    const int n4valid = NE * DCOL / 4;        // 6,400,000
    const int n4tot = NE_PAD * DCOL / 4;      // 6,406,144
    int i = ((int)blockIdx.x - ngemm) * (NW * 64) + tid;
    const int stride = ((int)gridDim.x - ngemm) * (NW * 64);
    for (; i < n4tot; i += stride) {
      float x = 0.f, y = 0.f, z = 0.f, w = 0.f;
      if (i < n4valid) {
        float4 v = ((const float4*)cvt_src)[i];
        x = v.x; y = v.y; z = v.z; w = v.w;
      }
      union { unsigned short u[4]; uint2 v2; } o;
      o.u[0] = f2bf(x); o.u[1] = f2bf(y); o.u[2] = f2bf(z); o.u[3] = f2bf(w);
      ((uint2*)cvt_dst)[i] = o.v2;
    }
    return;
  }

  const int lane = tid & 63;
  const int wv = tid >> 6;
  const int wm = wv / WN, wn = wv % WN;

  int m_t, n_t;
  if (SWZ) {
    int xcd = blockIdx.x & 7;
    int l = blockIdx.x >> 3;
    int w = xcd * ((MT * NT) >> 3) + l;  // bijective: MT*NT % 8 == 0
    n_t = w / MT; m_t = w % MT;
  } else {
    m_t = blockIdx.x % MT; n_t = blockIdx.x / MT;
  }
  const int m0 = m_t * BM;
  const int n0 = n_t * BN;
  const int rbytes = K * 2;

  f32x4 acc[FRm][FRn];
  #pragma unroll
  for (int i = 0; i < FRm; ++i)
    #pragma unroll
    for (int j = 0; j < FRn; ++j) acc[i][j] = (f32x4){0.f, 0.f, 0.f, 0.f};

  const int srow = lane >> 3;   // row within 8-row chunk
  const int scol = lane & 7;    // dest 16B unit within row
  const int nkt = K >> 6;       // K / 64

  auto stage = [&](int kt, int buf) {
    #pragma unroll
    for (int j = 0; j < CPW_A; ++j) {
      const int chunk = wv * CPW_A + j;
      const int r = chunk * 8 + srow;
      const int c = scol ^ (r & 7);
      gload16((const uint8_t*)A + (size_t)(m0 + r) * rbytes + kt * 128 + c * 16,
              &smem[buf * BUFSZ + chunk * 1024]);
    }
    #pragma unroll
    for (int j = 0; j < CPW_B; ++j) {
      const int chunk = wv * CPW_B + j;
      const int r = chunk * 8 + srow;
      const int c = scol ^ (r & 7);
      gload16((const uint8_t*)B + (size_t)(n0 + r) * rbytes + kt * 128 + c * 16,
              &smem[buf * BUFSZ + TILE_A + chunk * 1024]);
    }
  };
  auto compute = [&](int buf) {
    const uint8_t* sa = &smem[buf * BUFSZ];
    const uint8_t* sb = sa + TILE_A;
    #pragma unroll
    for (int kk = 0; kk < 2; ++kk) {
      s16x8 af[FRm], bfv[FRn];
      #pragma unroll
      for (int f = 0; f < FRm; ++f) {
        const int ra = (wm * FRm + f) * 16 + (lane & 15);
        const int ca = (kk * 4 + (lane >> 4)) ^ (ra & 7);
        af[f] = *(const s16x8*)&sa[ra * 128 + ca * 16];
      }
      #pragma unroll
      for (int f = 0; f < FRn; ++f) {
        const int rb = (wn * FRn + f) * 16 + (lane & 15);
        const int cb = (kk * 4 + (lane >> 4)) ^ (rb & 7);
        bfv[f] = *(const s16x8*)&sb[rb * 128 + cb * 16];
      }
      #pragma unroll
      for (int fm = 0; fm < FRm; ++fm)
        #pragma unroll
        for (int fn = 0; fn < FRn; ++fn)
          acc[fm][fn] = __builtin_amdgcn_mfma_f32_16x16x32_bf16(
              af[fm], bfv[fn], acc[fm][fn], 0, 0, 0);
    }
  };

  // prologue: two tiles in flight (2*SOPS outstanding loads/wave)
  stage(0, 0);
  stage(1, 1);
  // main loop: wait until only the NEXT tile's SOPS loads remain in flight
  for (int kt = 0; kt < nkt - 1; ++kt) {
    const int cur = kt & 1;
    waitcnt_vm<SOPS>();
    __builtin_amdgcn_sched_barrier(0);
    __builtin_amdgcn_s_barrier();          // all waves: buf[cur] ready
    __builtin_amdgcn_sched_barrier(0);
    compute(cur);
    __builtin_amdgcn_sched_barrier(0);
    __builtin_amdgcn_s_barrier();          // all waves done reading buf[cur]
    __builtin_amdgcn_sched_barrier(0);
    if (kt + 2 < nkt) stage(kt + 2, cur);  // refill freed buffer
  }
  // peeled last tile: drain fully
  waitcnt_vm<0>();
  __builtin_amdgcn_sched_barrier(0);
  __builtin_amdgcn_s_barrier();
  __builtin_amdgcn_sched_barrier(0);
  compute((nkt - 1) & 1);

  const int rl = lane >> 4, cl = lane & 15;
  #pragma unroll
  for (int fm = 0; fm < FRm; ++fm)
    #pragma unroll
    for (int fn = 0; fn < FRn; ++fn)
      #pragma unroll
      for (int j = 0; j < 4; ++j) {
        int gm = m0 + (wm * FRm + fm) * 16 + rl * 4 + j;
        int gn = n0 + (wn * FRn + fn) * 16 + cl;
        if (gn < Nc) {
          float v = acc[fm][fn][j];
          if (EPI) v = fmaxf(v + bias[gn], 0.f);
          C[(size_t)gm * Nc + gn] = v;
        }
      }
}

// ---------------------------------------------------------------------------
// K3: per-triple: attn logits+softmax (fused), Weff, contraction, n2.
// (R7-proven standalone version.)
// ---------------------------------------------------------------------------
__global__ __launch_bounds__(256, 2)
void triple_core(const int* __restrict__ heads, const int* __restrict__ rels,
                 const int* __restrict__ tails, const float* __restrict__ ew,
                 const float* __restrict__ rw, const float* __restrict__ wc,
                 const float* __restrict__ hid, const float* __restrict__ w2,
                 const float* __restrict__ b2, float* __restrict__ attn_out,
                 unsigned short* __restrict__ x1b, float* __restrict__ n2) {
  __shared__ float hs[512], rs[512], ts[512];
  __shared__ __align__(16) float W123[4096][4];   // 64 KB
  __shared__ float att[8];
  __shared__ float wred[4][8];
  __shared__ float red[256];
  int b = blockIdx.x, tid = threadIdx.x;
  int lane = tid & 63, wid = tid >> 6;
  const float* hp_ = ew + (size_t)heads[b] * DCOL;
  const float* rp_ = rw + (size_t)rels[b] * DCOL;
  const float* tp_ = ew + (size_t)tails[b] * DCOL;
  float la[8] = {0, 0, 0, 0, 0, 0, 0, 0};
  #pragma unroll
  for (int it = 0; it < 2; ++it) {
    int d = it * 256 + tid;
    hs[d] = hp_[d]; rs[d] = rp_[d]; ts[d] = tp_[d];
    float hv = hid[(size_t)b * DCOL + d];
    #pragma unroll
    for (int c = 0; c < 8; ++c) la[c] = fmaf(hv, w2[d * 8 + c], la[c]);
  }
  #pragma unroll
  for (int off = 32; off > 0; off >>= 1)
    #pragma unroll
    for (int c = 0; c < 8; ++c) la[c] += __shfl_down(la[c], off);
  if (lane == 0)
    #pragma unroll
    for (int c = 0; c < 8; ++c) wred[wid][c] = la[c];
  __syncthreads();
  if (tid == 0) {
    float lg[8];
    #pragma unroll
    for (int c = 0; c < 8; ++c)
      lg[c] = wred[0][c] + wred[1][c] + wred[2][c] + wred[3][c] + b2[c];
    float mx = lg[0];
    #pragma unroll
    for (int c = 1; c < 8; ++c) mx = fmaxf(mx, lg[c]);
    float e[8], s = 0.f;
    #pragma unroll
    for (int c = 0; c < 8; ++c) { e[c] = expf(lg[c] - mx); s += e[c]; }
    #pragma unroll
    for (int c = 0; c < 8; ++c) {
      float a = e[c] / s;
      att[c] = a;
      attn_out[(size_t)b * 8 + c] = a;
    }
  }
  __syncthreads();
  #pragma unroll
  for (int it = 0; it < 16; ++it) {
    int idx = it * 256 + tid;
    float w = 0.f;
    #pragma unroll
    for (int c = 0; c < 8; ++c) w = fmaf(att[c], wc[c * 4096 + idx], w);
    int s = idx & 15, q = (idx >> 4) & 15, p = idx >> 8;
    W123[idx][0] = w;                     // [p][q][s]
    W123[(q * 16 + s) * 16 + p][1] = w;   // [q][s][p]
    W123[(p * 16 + s) * 16 + q][2] = w;   // [p][s][q]
  }
  __syncthreads();

  const int so = tid & 15;
  const int i0 = tid >> 4, i1 = i0 + 16;
  float h0[16], r0[16], t0[16], h1[16], r1[16], t1[16];
  #pragma unroll
  for (int k = 0; k < 16; ++k) {
    h0[k] = hs[i0 * 16 + k]; r0[k] = rs[i0 * 16 + k]; t0[k] = ts[i0 * 16 + k];
    h1[k] = hs[i1 * 16 + k]; r1[k] = rs[i1 * 16 + k]; t1[k] = ts[i1 * 16 + k];
  }
  float a10 = 0.f, a20 = 0.f, a30 = 0.f, a11 = 0.f, a21 = 0.f, a31 = 0.f;
  const float4* wp = (const float4*)&W123[so][0];   // per-thread base
  #pragma unroll
  for (int u = 0; u < 16; ++u) {
    #pragma unroll
    for (int v = 0; v < 16; ++v) {
      float4 w = wp[u * 256 + v * 16];   // byte off = u*4096+v*256 (imm)
      a10 = fmaf(h0[u] * r0[v], w.x, a10);
      a20 = fmaf(r0[u] * t0[v], w.y, a20);
      a30 = fmaf(h0[u] * t0[v], w.z, a30);
      a11 = fmaf(h1[u] * r1[v], w.x, a11);
      a21 = fmaf(r1[u] * t1[v], w.y, a21);
      a31 = fmaf(h1[u] * t1[v], w.z, a31);
    }
  }
  x1b[(size_t)b * 512 + i0 * 16 + so] = f2bf(a10);
  x1b[(size_t)b * 512 + i1 * 16 + so] = f2bf(a11);
  red[tid] = a10 * a10 + a20 * a20 + a30 * a30
           + a11 * a11 + a21 * a21 + a31 * a31;
  __syncthreads();
  for (int s = 128; s > 0; s >>= 1) {
    if (tid < s) red[tid] += red[tid + s];
    __syncthreads();
  }
  if (tid == 0) n2[b] = red[0];
}

// ---------------------------------------------------------------------------
// K5: factors. factor1 = sum(n1)/B; factor2 = sum(n2)/B; factor3 geometric.
// ---------------------------------------------------------------------------
__global__ __launch_bounds__(256)
void finalize(const float* __restrict__ n1, const float* __restrict__ n2,
              const float* __restrict__ wc, float* __restrict__ out) {
  int tid = threadIdx.x;
  __shared__ float red[256];
  float a = 0.f;
  for (int i = tid; i < NB; i += 256) a += n1[i];
  red[tid] = a; __syncthreads();
  for (int s = 128; s > 0; s >>= 1) { if (tid < s) red[tid] += red[tid + s]; __syncthreads(); }
  if (tid == 0) out[F1_OFF] = red[0] / (float)NB;
  __syncthreads();
  a = 0.f;
  for (int i = tid; i < NB; i += 256) a += n2[i];
  red[tid] = a; __syncthreads();
  for (int s = 128; s > 0; s >>= 1) { if (tid < s) red[tid] += red[tid + s]; __syncthreads(); }
  if (tid == 0) out[F2_OFF] = red[0] / (float)NB;
  __syncthreads();

  int c = tid >> 5, l = tid & 31;
  float tot = 0.f, cx = 0.f, cy = 0.f, cz = 0.f;
  for (int e = l; e < 4096; e += 32) {
    float w = fabsf(wc[c * 4096 + e]);
    int z = e & 15, y = (e >> 4) & 15, x = e >> 8;
    tot += w; cx += w * x; cy += w * y; cz += w * z;
  }
  #pragma unroll
  for (int off = 16; off > 0; off >>= 1) {
    tot += __shfl_down(tot, off);
    cx += __shfl_down(cx, off);
    cy += __shfl_down(cy, off);
    cz += __shfl_down(cz, off);
  }
  __shared__ float cent[8][3];
  if (l == 0) { cent[c][0] = cx / tot; cent[c][1] = cy / tot; cent[c][2] = cz / tot; }
  __syncthreads();
  if (tid == 0) {
    float f3 = 0.f;
    for (int i = 0; i < 8; ++i) {
      float mn = 1e30f;
      for (int j = 0; j < 8; ++j) {
        if (j == i) continue;
        float dx = cent[i][0] - cent[j][0];
        float dy = cent[i][1] - cent[j][1];
        float dz = cent[i][2] - cent[j][2];
        float d = sqrtf(dx * dx + dy * dy + dz * dz);
        mn = fminf(mn, d);
      }
      f3 += logf(mn + 1e-6f);
    }
    out[F3_OFF] = -f3 / 8.f;
  }
}

// ---------------------------------------------------------------------------
extern "C" void kernel_launch(void* const* d_in, const int* in_sizes, int n_in,
                              void* d_out, int out_size, void* d_ws, size_t ws_size,
                              hipStream_t stream) {
  const int* heads = (const int*)d_in[0];
  const int* rels = (const int*)d_in[1];
  const int* tails = (const int*)d_in[2];
  const float* ew = (const float*)d_in[3];
  const float* rw = (const float*)d_in[4];
  const float* wc = (const float*)d_in[5];
  const float* w1 = (const float*)d_in[6];
  const float* b1 = (const float*)d_in[7];
  const float* w2 = (const float*)d_in[8];
  const float* b2 = (const float*)d_in[9];
  float* out = (float*)d_out;

  uint8_t* ws = (uint8_t*)d_ws;
  const size_t EWB_SZ = (size_t)NE_PAD * DCOL * 2;   // 51,249,152
  unsigned short* ewb = (unsigned short*)ws;
  unsigned short* hrb = (unsigned short*)(ws + EWB_SZ);
  unsigned short* w1t = (unsigned short*)(ws + EWB_SZ + 2097152);
  float* hid = (float*)(ws + EWB_SZ + 2097152 + 1048576);
  unsigned short* x1b = (unsigned short*)(ws + EWB_SZ + 2097152 + 1048576 + 2097152);
  float* n1 = (float*)(ws + EWB_SZ + 2097152 + 1048576 + 2097152 + 1048576);
  float* n2 = n1 + NB;

  prep<<<NB + 512, 256, 0, stream>>>(heads, rels, tails, ew, rw, w1,
                                     hrb, w1t, n1);
  // MLP GEMM (blocks 0..127: 64x64 tiles, 2x2 waves, FR 2x2, K=1024)
  // + entity_w fp32->bf16 cvt (blocks 128..2175, grid-stride, 5 blocks/CU)
  gemm_nt<1, 2, 2, 2, 2, 0, 16, 1><<<128 + 2048, 256, 0, stream>>>(
      hrb, w1t, hid, b1, 1024, 512, 8, ew, ewb, 128);
  triple_core<<<NB, 256, 0, stream>>>(heads, rels, tails, ew, rw, wc,
                                      hid, w2, b2, out + ATTN_OFF, x1b, n2);
  // scores GEMM: proven R7 config — 128x128 tiles, 4 waves (2x2, FR 4x4),
  // MT=8, NT=391, K=512, XCD-ownership swizzle
  gemm_nt<0, 2, 2, 4, 4, 1, 8, 0><<<3128, 256, 0, stream>>>(
      x1b, ewb, out, nullptr, 512, NE, 391, nullptr, nullptr, 0);
  finalize<<<1, 256, 0, stream>>>(n1, n2, wc, out);
}